// Round 21
// baseline (117.424 us; speedup 1.0000x reference)
//
#include <hip/hip_runtime.h>
#include <math.h>

#define NS 5000
#define SS 10
#define KK 20
#define HC 102
#define NBIN 32
#define BINW 16.0f
#define NPB 20           // prep/scatter blocks: ceil(5000/256)
#define CAP 192          // per-wave candidate capacity (P(overflow) ~ 0)

// Wave-level LDS sync: drain LDS ops + compiler ordering. Waves own private
// LDS slices; no block barrier needed (escalation may diverge between waves).
#define WAVE_SYNC() __asm__ volatile("s_waitcnt lgkmcnt(0)" ::: "memory")

// ---------- Kernel 1: stroke records + per-block bin counts (r12 verbatim) ----------
__global__ void __launch_bounds__(256) prep_kernel(
        const float* __restrict__ cs, const float* __restrict__ ce,
        const float* __restrict__ cc, const float* __restrict__ loc,
        const float* __restrict__ color, const float* __restrict__ width,
        float* __restrict__ sdata, float4* __restrict__ ctab,
        int* __restrict__ binCntP) {
    __shared__ int4 lcnt4[NBIN*NBIN/4];          // int4 decl guarantees 16B alignment
    int* lcnt = (int*)lcnt4;
    int t = threadIdx.x;
    lcnt4[t] = make_int4(0, 0, 0, 0);
    __syncthreads();
    int i = blockIdx.x * 256 + t;
    if (i < NS) {
        float lx = loc[i*2+0], ly = loc[i*2+1];
        float sx = cs[i*2+0] + lx, sy = cs[i*2+1] + ly;
        float ex = ce[i*2+0] + lx, ey = ce[i*2+1] + ly;
        float px = cc[i*2+0] + lx, py = cc[i*2+1] + ly;
        float qx[SS], qy[SS];
        #pragma unroll
        for (int j = 0; j < SS; ++j) {
            float tt = (float)j * (1.0f / 9.0f);   // linspace(0,1,10) step in fp32
            float omt = 1.0f - tt;
            float omt2 = omt * omt, t2 = tt * tt;
            qx[j] = px + omt2 * (sx - px) + t2 * (ex - px);
            qy[j] = py + omt2 * (sy - py) + t2 * (ey - py);
            sdata[i*32 + 2*j + 0] = qx[j];
            sdata[i*32 + 2*j + 1] = qy[j];
        }
        #pragma unroll
        for (int sg = 0; sg < 9; ++sg) {
            float bx = qx[sg+1] - qx[sg], by = qy[sg+1] - qy[sg];
            sdata[i*32 + 20 + sg] = 1.0f / (bx*bx + by*by);   // full precision
        }
        sdata[i*32 + 29] = 0.0f; sdata[i*32 + 30] = 0.0f; sdata[i*32 + 31] = 0.0f;
        ctab[i] = make_float4(color[i*3+0], color[i*3+1], color[i*3+2], width[i]);
        int b0 = min(max((int)(lx * (1.0f/BINW)), 0), NBIN-1);
        int b1 = min(max((int)(ly * (1.0f/BINW)), 0), NBIN-1);
        atomicAdd(&lcnt[b0*NBIN + b1], 1);
    }
    __syncthreads();
    ((int4*)binCntP)[blockIdx.x * 256 + t] = lcnt4[t];
}

// ---------- Kernel 2: redundant per-block scan + CSR scatter (r12 verbatim) ----------
__global__ void __launch_bounds__(256) scatter_kernel(
        const float* __restrict__ loc, const int* __restrict__ binCntP,
        int* __restrict__ binStart, float2* __restrict__ sxy, int* __restrict__ sid) {
    __shared__ int fill[NBIN*NBIN];
    __shared__ int wsum[4];
    int t = threadIdx.x, lane = t & 63, w = t >> 6;
    int mb = blockIdx.x;
    int4 tot = make_int4(0,0,0,0), bel = make_int4(0,0,0,0);
    for (int b = 0; b < NPB; ++b) {
        int4 v = ((const int4*)binCntP)[b * 256 + t];
        tot.x += v.x; tot.y += v.y; tot.z += v.z; tot.w += v.w;
        if (b < mb) { bel.x += v.x; bel.y += v.y; bel.z += v.z; bel.w += v.w; }
    }
    int s0 = tot.x, s1 = s0 + tot.y, s2 = s1 + tot.z, s3 = s2 + tot.w;
    int x = s3;
    #pragma unroll
    for (int off = 1; off < 64; off <<= 1) {
        int y = __shfl_up(x, off, 64);
        if (lane >= off) x += y;
    }
    if (lane == 63) wsum[w] = x;
    __syncthreads();
    int woff = 0;
    #pragma unroll
    for (int i = 0; i < 4; ++i) woff += (i < w) ? wsum[i] : 0;
    int texcl = woff + x - s3;           // exclusive prefix of this thread's 4 bins
    fill[4*t+0] = texcl      + bel.x;
    fill[4*t+1] = texcl + s0 + bel.y;
    fill[4*t+2] = texcl + s1 + bel.z;
    fill[4*t+3] = texcl + s2 + bel.w;
    if (mb == 0) {                       // publish global scan for topk
        binStart[4*t+1] = texcl + s0;
        binStart[4*t+2] = texcl + s1;
        binStart[4*t+3] = texcl + s2;
        binStart[4*t+4] = texcl + s3;
        if (t == 0) binStart[0] = 0;
    }
    __syncthreads();
    int i = mb * 256 + t;
    if (i < NS) {
        float l0 = loc[i*2+0], l1 = loc[i*2+1];
        int b0 = min(max((int)(l0 * (1.0f/BINW)), 0), NBIN-1);
        int b1 = min(max((int)(l1 * (1.0f/BINW)), 0), NBIN-1);
        int pos = atomicAdd(&fill[b0*NBIN + b1], 1);
        sxy[pos] = make_float2(l0, l1);
        sid[pos] = i;
    }
}

// ---------- Kernel 3: per-cell top-20 (r19 verbatim: exact, batched gathers) ----------
__global__ void __launch_bounds__(256) topk_kernel(const float* __restrict__ loc,
                                                   const float* __restrict__ width,
                                                   const float2* __restrict__ sxy,
                                                   const int* __restrict__ sid,
                                                   const int* __restrict__ binStart,
                                                   int* __restrict__ idcs,
                                                   float* __restrict__ wk) {
    __shared__ unsigned long long sk[4][CAP];
    int w = threadIdx.x >> 6, lane = threadIdx.x & 63;
    int cell = blockIdx.x * 4 + w;                 // grid covers exactly HC*HC
    int ci = cell / HC, cj = cell - ci * HC;
    const float dc = 512.0f / 101.0f;              // linspace(0,512,102) step in fp32
    float c0 = (float)ci * dc;
    float c1 = (float)cj * dc;
    unsigned long long below = (1ull << lane) - 1ull;

    float R = 26.0f;                               // E[cnt] ~ 40; P(cnt<20) ~ 2e-4
    int cnt = 0;
    for (int attempt = 0; attempt < 5; ++attempt) {
        float R2 = R * R;
        int base = 0;
        int by0 = max((int)((c0 - R) * (1.0f/BINW)), 0);
        int by1 = min((int)((c0 + R) * (1.0f/BINW)), NBIN-1);
        int bx0 = max((int)((c1 - R) * (1.0f/BINW)), 0);
        int bx1 = min((int)((c1 + R) * (1.0f/BINW)), NBIN-1);
        int nrows = by1 - by0 + 1;
        if (nrows <= 6) {
            int rs[6], re[6];
            #pragma unroll
            for (int r = 0; r < 6; ++r) {
                bool va = (r < nrows);
                int by = va ? (by0 + r) : by0;
                rs[r] = binStart[by*NBIN + bx0];
                re[r] = va ? binStart[by*NBIN + bx1 + 1] : rs[r];
            }
            float2 pr[6]; int idr[6];
            #pragma unroll
            for (int r = 0; r < 6; ++r) {          // all gathers in flight together
                int t  = rs[r] + lane;
                int tc = max(min(t, re[r] - 1), 0);
                pr[r]  = sxy[tc];
                idr[r] = sid[tc];
            }
            #pragma unroll
            for (int r = 0; r < 6; ++r) {
                int t = rs[r] + lane;
                float dx = c0 - pr[r].x, dy = c1 - pr[r].y;
                float d = dx*dx + dy*dy;
                bool pred = (t < re[r]) && (d < R2);
                unsigned long long mask = __ballot(pred);
                int pos = base + __popcll(mask & below);
                if (pred && pos < CAP)
                    sk[w][pos] = ((unsigned long long)__float_as_uint(d) << 32)
                               | (unsigned int)idr[r];
                base += __popcll(mask);
                for (int t0 = rs[r] + 64; t0 < re[r]; t0 += 64) {  // exact tail
                    int t2  = t0 + lane;
                    int tc2 = min(t2, re[r] - 1);
                    float2 p = sxy[tc2];
                    float ex = c0 - p.x, ey = c1 - p.y;
                    float d2 = ex*ex + ey*ey;
                    bool p2 = (t2 < re[r]) && (d2 < R2);
                    unsigned long long m2 = __ballot(p2);
                    int pos2 = base + __popcll(m2 & below);
                    if (p2 && pos2 < CAP)
                        sk[w][pos2] = ((unsigned long long)__float_as_uint(d2) << 32)
                                    | (unsigned int)sid[tc2];
                    base += __popcll(m2);
                }
            }
        } else {
            for (int by = by0; by <= by1; ++by) {  // escalated windows: serial path
                int s = binStart[by*NBIN + bx0];
                int e = binStart[by*NBIN + bx1 + 1];
                for (int t0 = s; t0 < e; t0 += 64) {
                    int t = t0 + lane;
                    int tc = min(t, e - 1);
                    float2 p = sxy[tc];
                    float dx = c0 - p.x, dy = c1 - p.y;
                    float d = dx*dx + dy*dy;
                    bool pred = (t < e) && (d < R2);
                    unsigned long long mask = __ballot(pred);
                    int pos = base + __popcll(mask & below);
                    if (pred && pos < CAP)
                        sk[w][pos] = ((unsigned long long)__float_as_uint(d) << 32)
                                   | (unsigned int)sid[tc];
                    base += __popcll(mask);
                }
            }
        }
        cnt = base;
        if (cnt >= KK) break;                      // includes overflow -> fallback below
        R *= 1.6f;
    }
    WAVE_SYNC();

    if (cnt >= KK && cnt <= CAP) {
        if (cnt <= 64) {
            unsigned long long k0 = (lane < cnt) ? sk[w][lane] : ~0ull;
            int r0 = 0;
            int j = 0;
            #pragma unroll 1
            for (; j + 4 <= cnt; j += 4) {
                unsigned long long a = sk[w][j],   b = sk[w][j+1];
                unsigned long long c = sk[w][j+2], d = sk[w][j+3];
                r0 += (int)(a < k0) + (int)(b < k0) + (int)(c < k0) + (int)(d < k0);
            }
            for (; j < cnt; ++j) r0 += (int)(sk[w][j] < k0);
            if (r0 < KK && lane < cnt) {
                int idx = (int)(unsigned int)(k0 & 0xffffffffull);
                idcs[cell*KK + r0] = idx;
                wk[cell*KK + r0]   = width[idx];
            }
        } else {
            unsigned long long k0 = (lane       < cnt) ? sk[w][lane]       : ~0ull;
            unsigned long long k1 = (lane + 64  < cnt) ? sk[w][lane + 64]  : ~0ull;
            unsigned long long k2 = (lane + 128 < cnt) ? sk[w][lane + 128] : ~0ull;
            int r0 = 0, r1 = 0, r2 = 0;
            #pragma unroll 1
            for (int j = 0; j < cnt; ++j) {
                unsigned long long a = sk[w][j];
                r0 += (int)(a < k0); r1 += (int)(a < k1); r2 += (int)(a < k2);
            }
            if (r0 < KK && lane < cnt) {
                int idx = (int)(unsigned int)(k0 & 0xffffffffull);
                idcs[cell*KK + r0] = idx;  wk[cell*KK + r0] = width[idx];
            }
            if (r1 < KK && lane + 64 < cnt) {
                int idx = (int)(unsigned int)(k1 & 0xffffffffull);
                idcs[cell*KK + r1] = idx;  wk[cell*KK + r1] = width[idx];
            }
            if (r2 < KK && lane + 128 < cnt) {
                int idx = (int)(unsigned int)(k2 & 0xffffffffull);
                idcs[cell*KK + r2] = idx;  wk[cell*KK + r2] = width[idx];
            }
        }
    } else {
        if (lane == 0) {                 // exactness fallback (statistically never)
            float bd[KK]; int bi[KK];
            for (int k = 0; k < KK; ++k) { bd[k] = 3.4e38f; bi[k] = 0; }
            for (int n = 0; n < NS; ++n) {
                float dx = c0 - loc[n*2+0];
                float dy = c1 - loc[n*2+1];
                float d = dx*dx + dy*dy;
                if (d < bd[KK-1]) {
                    int p = KK - 1;
                    while (p > 0 && bd[p-1] > d) { bd[p] = bd[p-1]; bi[p] = bi[p-1]; --p; }
                    bd[p] = d; bi[p] = n;
                }
            }
            for (int k = 0; k < KK; ++k) {
                idcs[cell*KK + k] = bi[k];
                wk[cell*KK + k]   = width[bi[k]];
            }
        }
    }
}

// ---------- Kernel 4: render — LDS staging for BOTH stroke records and wk ----------
// r20 proved the divergent L1/L2 load path was render's bottleneck (44->33 us
// via LDS-staged records). This round removes the LAST in-loop global loads:
// the 4 wk gathers per k. A 16x16 block's bilinear corner cells lie in a 6x6
// window at base max(0, floor((b*16+0.5)*sc-0.5)): pixel-floor span over 16
// pixels is 15*0.19921875 < 3, +1 for the x1/y1 corner, +clamp. Stage 36
// cells x 20 floats (2.9 KB, float4), blend in-loop from LDS with identical
// arithmetic on identical values -> bit-identical. Total LDS 50.2 KB -> still
// 3 blocks/CU. sg-loop + softmax numerics frozen.
__global__ void __launch_bounds__(256, 4) render_kernel(const float* __restrict__ sdata,
                                                        const float4* __restrict__ ctab,
                                                        const int* __restrict__ idcs,
                                                        const float* __restrict__ wk,
                                                        float* __restrict__ out) {
    __shared__ float  srec[16*20*32];        // 40960 B: staged stroke records
    __shared__ float4 scol[16*20];           //  5120 B: staged colors
    __shared__ int    sidx[16*20];           //  1280 B: staged stroke ids
    __shared__ float  swk[6*6*20];           //  2880 B: staged wk window
    int tt0 = threadIdx.x, lane = tt0 & 63, wq = tt0 >> 6;
    int x = blockIdx.x * 16 + ((wq & 1) << 3) + (lane & 7);   // wave = 8x8 pixel tile
    int y = blockIdx.y * 16 + ((wq >> 1) << 3) + (lane >> 3);
    int cy0 = (blockIdx.y * 16 * 51) >> 8;   // stroke window origin (<=98)
    int cx0 = (blockIdx.x * 16 * 51) >> 8;
    const float sc = 102.0f / 512.0f;        // exact in fp32

    // wk window origin: first-pixel bilinear floor, clamped at 0
    int wy0 = max(0, (int)floorf(((float)(blockIdx.y * 16) + 0.5f) * sc - 0.5f));
    int wx0 = max(0, (int)floorf(((float)(blockIdx.x * 16) + 0.5f) * sc - 0.5f));

    // ---- stage cell idx lists, then records, colors, wk window ----
    for (int s = tt0; s < 16*20; s += 256) {
        int c = s / 20, k = s - c * 20;
        int cellI = (cy0 + (c >> 2)) * HC + cx0 + (c & 3);
        sidx[s] = idcs[cellI * KK + k];
    }
    __syncthreads();
    for (int s = tt0; s < 16*20*8; s += 256) {   // 8 float4 per record
        int r = s >> 3, wd = s & 7;
        ((float4*)srec)[s] = ((const float4*)sdata)[sidx[r] * 8 + wd];
    }
    for (int s = tt0; s < 16*20; s += 256) scol[s] = ctab[sidx[s]];
    for (int s = tt0; s < 36*5; s += 256) {      // 5 float4 per wk cell row
        int c = s / 5, q = s - c * 5;
        int gy = min(HC - 1, wy0 + c / 6);
        int gx = min(HC - 1, wx0 + c % 6);
        ((float4*)swk)[c*5 + q] = ((const float4*)(wk + (gy * HC + gx) * KK))[q];
    }
    __syncthreads();

    const float df = 512.0f / 511.0f;        // linspace(0,512,512) step in fp32
    float p0 = (float)y * df;                // H-coordinate
    float p1 = (float)x * df;                // W-coordinate
    int cy = (y * 51) >> 8;                  // floor(y*102/512), exact vs fp32 ref
    int cx = (x * 51) >> 8;
    int lc = ((cy - cy0) << 2) + (cx - cx0); // local cell in the 4x4 stroke window

    // jax.image.resize linear: half-pixel centers + edge-normalized == clamped bilinear
    float iny = ((float)y + 0.5f) * sc - 0.5f;
    float inx = ((float)x + 0.5f) * sc - 0.5f;
    float y0f = floorf(iny), x0f = floorf(inx);
    float fy = iny - y0f, fx = inx - x0f;
    int y0 = min(max((int)y0f, 0), HC - 1);
    int y1 = min(max((int)y0f + 1, 0), HC - 1);
    int x0 = min(max((int)x0f, 0), HC - 1);
    int x1 = min(max((int)x0f + 1, 0), HC - 1);
    // local wk-window indices (proven in [0,5]: y0>=wy0, y1-wy0<=4; same for x)
    const float* w00 = swk + ((y0 - wy0) * 6 + (x0 - wx0)) * KK;
    const float* w01 = swk + ((y0 - wy0) * 6 + (x1 - wx0)) * KK;
    const float* w10 = swk + ((y1 - wy0) * 6 + (x0 - wx0)) * KK;
    const float* w11 = swk + ((y1 - wy0) * 6 + (x1 - wx0)) * KK;

    float m = -INFINITY, s = 0.0f;
    float a0 = 0.0f, a1 = 0.0f, a2 = 0.0f, wa = 0.0f;
    float D = INFINITY;

    #pragma unroll 4
    for (int k = 0; k < KK; ++k) {
        const float4* sp = (const float4*)(srec + (lc * 20 + k) * 32);
        float4 f0 = sp[0], f1 = sp[1], f2 = sp[2], f3 = sp[3], f4 = sp[4];
        float4 i0 = sp[5], i1 = sp[6], i2 = sp[7];
        float4 cw = scol[lc * 20 + k];
        float qx[10] = {f0.x, f0.z, f1.x, f1.z, f2.x, f2.z, f3.x, f3.z, f4.x, f4.z};
        float qy[10] = {f0.y, f0.w, f1.y, f1.w, f2.y, f2.w, f3.y, f3.w, f4.y, f4.w};
        float iv[9]  = {i0.x, i0.y, i0.z, i0.w, i1.x, i1.y, i1.z, i1.w, i2.x};
        float mink = INFINITY;
        #pragma unroll
        for (int sg = 0; sg < 9; ++sg) {
            float ax = qx[sg], ay = qy[sg];
            float bx = qx[sg+1] - ax, by = qy[sg+1] - ay;
            float pax = p0 - ax, pay = p1 - ay;
            float dot = bx * pax + by * pay;
            float tt = dot * iv[sg];
            tt = fminf(fmaxf(tt, 0.0f), 1.0f);
            float ccx = ax + tt * bx, ccy = ay + tt * by;
            float ddx = p0 - ccx, ddy = p1 - ccy;
            float d = ddx * ddx + ddy * ddy;
            mink = fminf(mink, d);
        }
        D = fminf(D, mink);
        float z = 100000.0f / (1e-8f + mink);    // IEEE div: exponent is rounding-sensitive
        float wkv = (1.0f - fy) * ((1.0f - fx) * w00[k] + fx * w01[k])
                  +          fy * ((1.0f - fx) * w10[k] + fx * w11[k]);
        // branchless online softmax (== subtract-max softmax, exp(0)==1 exactly)
        float nm  = fmaxf(m, z);
        float scl = __expf(m - nm);              // m=-inf first iter -> 0
        float e   = __expf(z - nm);
        s  = s  * scl + e;
        a0 = a0 * scl + cw.x * e;
        a1 = a1 * scl + cw.y * e;
        a2 = a2 * scl + cw.z * e;
        wa = wa * scl + wkv * e;
        m = nm;
    }
    float inv = 1.0f / s;
    float bs = wa * inv;
    float msk = 1.0f / (1.0f + __expf(-(bs - D)));   // sigmoid
    float o0 = a0 * inv * msk + (1.0f - msk) * 0.5f;
    float o1 = a1 * inv * msk + (1.0f - msk) * 0.5f;
    float o2 = a2 * inv * msk + (1.0f - msk) * 0.5f;
    int base = (y * 512 + x) * 3;
    out[base+0] = o0;
    out[base+1] = o1;
    out[base+2] = o2;
}

extern "C" void kernel_launch(void* const* d_in, const int* in_sizes, int n_in,
                              void* d_out, int out_size, void* d_ws, size_t ws_size,
                              hipStream_t stream) {
    const float* cs    = (const float*)d_in[0];  // curve_s (5000,2)
    const float* ce    = (const float*)d_in[1];  // curve_e (5000,2)
    const float* cc    = (const float*)d_in[2];  // curve_c (5000,2)
    const float* color = (const float*)d_in[3];  // color   (5000,3)
    const float* loc   = (const float*)d_in[4];  // location(5000,2)
    const float* width = (const float*)d_in[5];  // width   (5000,1)
    float* out = (float*)d_out;

    char* p = (char*)d_ws;
    float*  sdata    = (float*)p;                 p += NS * 32 * sizeof(float);       // 640000
    float4* ctab     = (float4*)p;                p += NS * sizeof(float4);           // 80000
    int*    idcs     = (int*)p;                   p += (size_t)HC*HC*KK*sizeof(int);  // 832320
    float*  wk       = (float*)p;                 p += (size_t)HC*HC*KK*sizeof(float);// 832320
    int*    binCntP  = (int*)p;                   p += NPB * NBIN*NBIN * sizeof(int); // 81920
    int*    binStart = (int*)p;                   p += 4112;                          // 1025 ints + pad
    float2* sxy      = (float2*)p;                p += NS * sizeof(float2);           // 40000
    int*    sid      = (int*)p;                   /* 20000 */

    prep_kernel   <<<NPB, 256, 0, stream>>>(cs, ce, cc, loc, color, width, sdata, ctab, binCntP);
    scatter_kernel<<<NPB, 256, 0, stream>>>(loc, binCntP, binStart, sxy, sid);
    topk_kernel   <<<(HC*HC)/4, 256, 0, stream>>>(loc, width, sxy, sid, binStart, idcs, wk);
    render_kernel <<<dim3(32, 32), 256, 0, stream>>>(sdata, ctab, idcs, wk, out);
}